// Round 1
// baseline (125.472 us; speedup 1.0000x reference)
//
#include <hip/hip_runtime.h>
#include <hip/hip_bf16.h>
#include <stdint.h>

#define S_LEN 2048
#define BATCH 4
#define HID 1024
#define M_ROWS (BATCH * S_LEN)   // 8192

typedef __attribute__((ext_vector_type(8))) short short8;
typedef __attribute__((ext_vector_type(4))) float f32x4;

__device__ __forceinline__ void gload_lds16(const void* g, void* l) {
  __builtin_amdgcn_global_load_lds(
      (const __attribute__((address_space(1))) unsigned int*)g,
      (__attribute__((address_space(3))) unsigned int*)l, 16, 0, 0);
}

// ---------------- fp32 -> bf16 conversion (hs, Wq, Wk) ----------------
__global__ __launch_bounds__(256) void convert_all(
    const float* __restrict__ hs, const float* __restrict__ wq,
    const float* __restrict__ wk,
    __hip_bfloat16* __restrict__ hs_bf, __hip_bfloat16* __restrict__ wq_bf,
    __hip_bfloat16* __restrict__ wk_bf) {
  const int NH = M_ROWS * HID;   // 8388608
  const int NW = HID * HID;      // 1048576
  int idx = (blockIdx.x * blockDim.x + threadIdx.x) * 4;
  const float* src;
  __hip_bfloat16* dst;
  int off;
  if (idx < NH)           { src = hs; dst = hs_bf; off = idx; }
  else if (idx < NH + NW) { src = wq; dst = wq_bf; off = idx - NH; }
  else                    { src = wk; dst = wk_bf; off = idx - NH - NW; }
  float4 v = *reinterpret_cast<const float4*>(src + off);
  __hip_bfloat16 tmp[4];
  tmp[0] = __float2bfloat16(v.x);
  tmp[1] = __float2bfloat16(v.y);
  tmp[2] = __float2bfloat16(v.z);
  tmp[3] = __float2bfloat16(v.w);
  *reinterpret_cast<ushort4*>(dst + off) = *reinterpret_cast<const ushort4*>(tmp);
}

// ---------------- shared 128x128xK NT GEMM core ----------------
// A: [>=128 rows][lda] bf16 row-major (tile base), B: [>=128 rows][ldb] bf16
// row-major. Computes acc[4][4] (each f32x4) = A_tile * B_tile^T for this
// block's 128x128 output tile. 256 threads = 4 waves in 2x2 (each 64x64).
__device__ __forceinline__ void gemm128_nt(
    const __hip_bfloat16* __restrict__ A, const __hip_bfloat16* __restrict__ B,
    int lda, int ldb, int Kdim, __hip_bfloat16* As, __hip_bfloat16* Bs,
    f32x4 acc[4][4]) {
  const int t = threadIdx.x;
  const int w = t >> 6;        // wave 0..3
  const int l = t & 63;        // lane
  const int srow = t >> 2;     // staging row 0..63 (issue 0); +64 for issue 1
  const int scol = (t & 3) * 8;
  const int lr = l & 15;
  const int lk = (l >> 4) * 8;
  const int wr = w >> 1, wc = w & 1;

  for (int kt = 0; kt < Kdim; kt += 32) {
    // stage A tile (128x32 bf16 = 8KB): 2 issues of 256 threads x 16B
    gload_lds16(A + (size_t)srow * lda + kt + scol,        As + w * 512);
    gload_lds16(A + (size_t)(srow + 64) * lda + kt + scol, As + 2048 + w * 512);
    gload_lds16(B + (size_t)srow * ldb + kt + scol,        Bs + w * 512);
    gload_lds16(B + (size_t)(srow + 64) * ldb + kt + scol, Bs + 2048 + w * 512);
    __syncthreads();   // drains vmcnt(0): LDS tile valid

    short8 fa[4], fb[4];
#pragma unroll
    for (int m = 0; m < 4; ++m)
      fa[m] = *reinterpret_cast<const short8*>(
          &As[(wr * 64 + m * 16 + lr) * 32 + lk]);
#pragma unroll
    for (int n = 0; n < 4; ++n)
      fb[n] = *reinterpret_cast<const short8*>(
          &Bs[(wc * 64 + n * 16 + lr) * 32 + lk]);
#pragma unroll
    for (int m = 0; m < 4; ++m)
#pragma unroll
      for (int n = 0; n < 4; ++n)
        acc[m][n] = __builtin_amdgcn_mfma_f32_16x16x32_bf16(
            fa[m], fb[n], acc[m][n], 0, 0, 0);
    __syncthreads();   // reads done before next stage overwrites
  }
}

// ---------------- Q/K projection: X @ W^T + b -> bf16 ----------------
// grid: (HID/128, M_ROWS/128, 2)  z=0 -> Q (Wq,bq), z=1 -> K (Wk,bk)
__global__ __launch_bounds__(256) void proj_gemm(
    const __hip_bfloat16* __restrict__ X,
    const __hip_bfloat16* __restrict__ Wq, const float* __restrict__ bq,
    const __hip_bfloat16* __restrict__ Wk, const float* __restrict__ bk,
    __hip_bfloat16* __restrict__ Qo, __hip_bfloat16* __restrict__ Ko) {
  __shared__ __hip_bfloat16 As[128 * 32];
  __shared__ __hip_bfloat16 Bs[128 * 32];
  const __hip_bfloat16* W = (blockIdx.z == 0) ? Wq : Wk;
  const float* bias = (blockIdx.z == 0) ? bq : bk;
  __hip_bfloat16* Out = (blockIdx.z == 0) ? Qo : Ko;
  const int bm = blockIdx.y, bn = blockIdx.x;

  f32x4 acc[4][4];
#pragma unroll
  for (int m = 0; m < 4; ++m)
#pragma unroll
    for (int n = 0; n < 4; ++n) acc[m][n] = (f32x4){0.f, 0.f, 0.f, 0.f};

  gemm128_nt(X + (size_t)bm * 128 * HID, W + (size_t)bn * 128 * HID,
             HID, HID, HID, As, Bs, acc);

  const int t = threadIdx.x, w = t >> 6, l = t & 63;
  const int wr = w >> 1, wc = w & 1;
  const int lr = l & 15, lg = l >> 4;
#pragma unroll
  for (int m = 0; m < 4; ++m)
#pragma unroll
    for (int n = 0; n < 4; ++n) {
      const int col = bn * 128 + wc * 64 + n * 16 + lr;
      const float bb = bias[col];
#pragma unroll
      for (int r = 0; r < 4; ++r) {
        const int row = bm * 128 + wr * 64 + m * 16 + lg * 4 + r;
        Out[(size_t)row * HID + col] = __float2bfloat16(acc[m][n][r] + bb);
      }
    }
}

// ---------------- scores: out[b] = (QK^T/128) * mask_r * mask_c ----------------
// grid: (S/128, S/128, BATCH)
__global__ __launch_bounds__(256) void scores_gemm(
    const __hip_bfloat16* __restrict__ Q, const __hip_bfloat16* __restrict__ Km,
    const float* __restrict__ mask, float* __restrict__ out) {
  __shared__ __hip_bfloat16 As[128 * 32];
  __shared__ __hip_bfloat16 Bs[128 * 32];
  const int b = blockIdx.z;
  const int bm = blockIdx.y, bn = blockIdx.x;

  f32x4 acc[4][4];
#pragma unroll
  for (int m = 0; m < 4; ++m)
#pragma unroll
    for (int n = 0; n < 4; ++n) acc[m][n] = (f32x4){0.f, 0.f, 0.f, 0.f};

  const __hip_bfloat16* A  = Q  + ((size_t)b * S_LEN + bm * 128) * HID;
  const __hip_bfloat16* Bp = Km + ((size_t)b * S_LEN + bn * 128) * HID;
  gemm128_nt(A, Bp, HID, HID, HID, As, Bs, acc);

  const int t = threadIdx.x, w = t >> 6, l = t & 63;
  const int wr = w >> 1, wc = w & 1;
  const int lr = l & 15, lg = l >> 4;
  const float inv = 1.0f / 128.0f;   // 1/sqrt(64) * 1/16 heads
#pragma unroll
  for (int m = 0; m < 4; ++m)
#pragma unroll
    for (int n = 0; n < 4; ++n) {
      const int col = bn * 128 + wc * 64 + n * 16 + lr;
      const float mc = mask[b * S_LEN + col] * inv;
#pragma unroll
      for (int r = 0; r < 4; ++r) {
        const int row = bm * 128 + wr * 64 + m * 16 + lg * 4 + r;
        const float mr = mask[b * S_LEN + row];
        out[(size_t)b * S_LEN * S_LEN + (size_t)row * S_LEN + col] =
            acc[m][n][r] * mc * mr;
      }
    }
}

extern "C" void kernel_launch(void* const* d_in, const int* in_sizes, int n_in,
                              void* d_out, int out_size, void* d_ws,
                              size_t ws_size, hipStream_t stream) {
  const float* hs   = (const float*)d_in[0];
  const float* mask = (const float*)d_in[1];
  const float* Wq   = (const float*)d_in[2];
  const float* bq   = (const float*)d_in[3];
  const float* Wk   = (const float*)d_in[4];
  const float* bk   = (const float*)d_in[5];
  float* out = (float*)d_out;

  char* ws = (char*)d_ws;
  __hip_bfloat16* hs_bf = (__hip_bfloat16*)(ws);                 // 16 MB
  __hip_bfloat16* wq_bf = (__hip_bfloat16*)(ws + 16777216);      //  2 MB
  __hip_bfloat16* wk_bf = (__hip_bfloat16*)(ws + 18874368);      //  2 MB
  __hip_bfloat16* q_bf  = (__hip_bfloat16*)(ws + 20971520);      // 16 MB
  __hip_bfloat16* k_bf  = (__hip_bfloat16*)(ws + 37748736);      // 16 MB
  // total ws use: 54,525,952 bytes

  hipLaunchKernelGGL(convert_all, dim3(10240), dim3(256), 0, stream,
                     hs, Wq, Wk, hs_bf, wq_bf, wk_bf);
  hipLaunchKernelGGL(proj_gemm, dim3(HID / 128, M_ROWS / 128, 2), dim3(256),
                     0, stream, hs_bf, wq_bf, bq, wk_bf, bk, q_bf, k_bf);
  hipLaunchKernelGGL(scores_gemm, dim3(S_LEN / 128, S_LEN / 128, BATCH),
                     dim3(256), 0, stream, q_bf, k_bf, mask, out);
}

// Round 2
// 90.007 us; speedup vs baseline: 1.3940x; 1.3940x over previous
//
#include <hip/hip_runtime.h>
#include <hip/hip_bf16.h>
#include <stdint.h>

#define S_LEN 2048
#define BATCH 4
#define HID 1024
#define M_ROWS (BATCH * S_LEN)   // 8192

typedef __attribute__((ext_vector_type(8))) short short8;
typedef __attribute__((ext_vector_type(4))) float f32x4;

__device__ __forceinline__ void gload_lds16(const __hip_bfloat16* g,
                                            __hip_bfloat16* l) {
  __builtin_amdgcn_global_load_lds(
      (const __attribute__((address_space(1))) unsigned int*)g,
      (__attribute__((address_space(3))) unsigned int*)l, 16, 0, 0);
}

// ---------------- fp32 -> bf16 conversion (hs, Wq, Wk) ----------------
__global__ __launch_bounds__(256) void convert_all(
    const float* __restrict__ hs, const float* __restrict__ wq,
    const float* __restrict__ wk,
    __hip_bfloat16* __restrict__ hs_bf, __hip_bfloat16* __restrict__ wq_bf,
    __hip_bfloat16* __restrict__ wk_bf) {
  const int NH = M_ROWS * HID;   // 8388608
  const int NW = HID * HID;      // 1048576
  int idx = (blockIdx.x * blockDim.x + threadIdx.x) * 4;
  const float* src;
  __hip_bfloat16* dst;
  int off;
  if (idx < NH)           { src = hs; dst = hs_bf; off = idx; }
  else if (idx < NH + NW) { src = wq; dst = wq_bf; off = idx - NH; }
  else                    { src = wk; dst = wk_bf; off = idx - NH - NW; }
  float4 v = *reinterpret_cast<const float4*>(src + off);
  __hip_bfloat16 tmp[4];
  tmp[0] = __float2bfloat16(v.x);
  tmp[1] = __float2bfloat16(v.y);
  tmp[2] = __float2bfloat16(v.z);
  tmp[3] = __float2bfloat16(v.w);
  *reinterpret_cast<ushort4*>(dst + off) = *reinterpret_cast<const ushort4*>(tmp);
}

// ---------------- 256x256 8-phase NT GEMM core ----------------
// 512 threads = 8 waves (2 M x 4 N), per-wave 128x64 output, BK=64,
// double-buffered 128 KiB LDS, XOR-swizzled (slot ^= row&7) to kill
// ds_read_b128 bank conflicts; counted vmcnt(4), raw s_barrier, setprio.
template <int NT>
__device__ __forceinline__ void gemm256_core(
    const __hip_bfloat16* __restrict__ A, const __hip_bfloat16* __restrict__ B,
    const int lda, const int ldb, __hip_bfloat16* lds, f32x4 acc[8][4]) {
  const int t = threadIdx.x;
  const int wid = t >> 6;
  const int l = t & 63;
  const int lr = l & 15;        // fragment row within 16
  const int lk = l >> 4;        // k-group 0..3
  const int wr = wid >> 2;      // wave row 0..1
  const int wc = wid & 3;       // wave col 0..3
  const int trow = t >> 3;      // staging row within 64-row issue
  const int tslot = (t & 7) ^ (trow & 7);   // pre-swizzled global 16B slot
  const int rsx = lr & 7;       // read-side xor

  __hip_bfloat16* const A0 = lds;
  __hip_bfloat16* const A1 = lds + 16384;
  __hip_bfloat16* const B0 = lds + 32768;
  __hip_bfloat16* const B1 = lds + 49152;

  short8 fa[4][2], fb[4][2];

#define STAGE_H(lb, gb, ld, half, kt) do {                                    \
    gload_lds16((gb) + (size_t)((half)*128 + 0  + trow) * (ld) + (kt)*64 +    \
                    tslot * 8,                                                \
                (lb) + ((half)*128 + 0) * 64 + wid * 512);                    \
    gload_lds16((gb) + (size_t)((half)*128 + 64 + trow) * (ld) + (kt)*64 +    \
                    tslot * 8,                                                \
                (lb) + ((half)*128 + 64) * 64 + wid * 512);                   \
  } while (0)

#define LDA_H(mh, Ac) do {                                                    \
    _Pragma("unroll") for (int m = 0; m < 4; ++m)                             \
    _Pragma("unroll") for (int kk = 0; kk < 2; ++kk)                          \
      fa[m][kk] = *reinterpret_cast<const short8*>(                           \
          (Ac) + (wr * 128 + (mh)*64 + m * 16 + lr) * 64 +                    \
          (((kk * 4 + lk) ^ rsx) * 8));                                       \
  } while (0)

#define LDB_H(nh, Bc) do {                                                    \
    _Pragma("unroll") for (int n = 0; n < 2; ++n)                             \
    _Pragma("unroll") for (int kk = 0; kk < 2; ++kk)                          \
      fb[(nh)*2 + n][kk] = *reinterpret_cast<const short8*>(                  \
          (Bc) + (wc * 64 + (nh)*32 + n * 16 + lr) * 64 +                     \
          (((kk * 4 + lk) ^ rsx) * 8));                                       \
  } while (0)

#define MFMA_Q(mh, nh) do {                                                   \
    __builtin_amdgcn_s_setprio(1);                                            \
    _Pragma("unroll") for (int m = 0; m < 4; ++m)                             \
    _Pragma("unroll") for (int n = 0; n < 2; ++n)                             \
    _Pragma("unroll") for (int kk = 0; kk < 2; ++kk)                          \
      acc[(mh)*4 + m][(nh)*2 + n] = __builtin_amdgcn_mfma_f32_16x16x32_bf16(  \
          fa[m][kk], fb[(nh)*2 + n][kk], acc[(mh)*4 + m][(nh)*2 + n], 0, 0, 0);\
    __builtin_amdgcn_s_setprio(0);                                            \
  } while (0)

#define CFENCE asm volatile("" ::: "memory")
#define BAR_PRE do { CFENCE; __builtin_amdgcn_s_barrier();                    \
    asm volatile("s_waitcnt lgkmcnt(0)" ::: "memory"); } while (0)
#define BAR_POST do { CFENCE; __builtin_amdgcn_s_barrier(); CFENCE; } while (0)

  // prologue: tile0 fully, tile1 B-halves
  STAGE_H(A0, A, lda, 0, 0); STAGE_H(A0, A, lda, 1, 0);
  STAGE_H(B0, B, ldb, 0, 0); STAGE_H(B0, B, ldb, 1, 0);
  STAGE_H(B1, B, ldb, 0, 1); STAGE_H(B1, B, ldb, 1, 1);
  asm volatile("s_waitcnt vmcnt(4)" ::: "memory");
  __builtin_amdgcn_s_barrier();
  CFENCE;

#pragma unroll 2
  for (int tt = 0; tt < NT; ++tt) {
    const int cur = tt & 1;
    __hip_bfloat16* const Ac = cur ? A1 : A0;
    __hip_bfloat16* const An = cur ? A0 : A1;
    __hip_bfloat16* const Bc = cur ? B1 : B0;
    // c0: quadrant (m 0..3, n 0..1); stage A-h0(tt+1)
    LDA_H(0, Ac); LDB_H(0, Bc);
    if (tt + 1 < NT) STAGE_H(An, A, lda, 0, tt + 1);
    BAR_PRE; MFMA_Q(0, 0); BAR_POST;
    // c1: quadrant (m 0..3, n 2..3); stage A-h1(tt+1)
    LDB_H(1, Bc);
    if (tt + 1 < NT) STAGE_H(An, A, lda, 1, tt + 1);
    BAR_PRE; MFMA_Q(0, 1); BAR_POST;
    // c2: quadrant (m 4..7, n 2..3); stage B-h0(tt+2) (same-parity buffer)
    LDA_H(1, Ac);
    if (tt + 2 < NT) STAGE_H(Bc, B, ldb, 0, tt + 2);
    BAR_PRE; MFMA_Q(1, 1); BAR_POST;
    // c3: quadrant (m 4..7, n 0..1); stage B-h1(tt+2); counted drain
    if (tt + 2 < NT) STAGE_H(Bc, B, ldb, 1, tt + 2);
    BAR_PRE; MFMA_Q(1, 0);
    asm volatile("s_waitcnt vmcnt(4)" ::: "memory");
    BAR_POST;
  }
#undef STAGE_H
#undef LDA_H
#undef LDB_H
#undef MFMA_Q
#undef CFENCE
#undef BAR_PRE
#undef BAR_POST
}

// ---------------- Q/K projection: X @ W^T + b -> bf16 ----------------
// grid: (HID/256, M_ROWS/256, 2)  z=0 -> Q, z=1 -> K
__global__ __launch_bounds__(512, 2) void proj_gemm(
    const __hip_bfloat16* __restrict__ X,
    const __hip_bfloat16* __restrict__ Wq, const float* __restrict__ bq,
    const __hip_bfloat16* __restrict__ Wk, const float* __restrict__ bk,
    __hip_bfloat16* __restrict__ Qo, __hip_bfloat16* __restrict__ Ko) {
  extern __shared__ char smem[];
  __hip_bfloat16* lds = reinterpret_cast<__hip_bfloat16*>(smem);
  const __hip_bfloat16* W = (blockIdx.z == 0) ? Wq : Wk;
  const float* bias = (blockIdx.z == 0) ? bq : bk;
  __hip_bfloat16* Out = (blockIdx.z == 0) ? Qo : Ko;
  const int bm = blockIdx.y, bn = blockIdx.x;

  f32x4 acc[8][4];
#pragma unroll
  for (int m = 0; m < 8; ++m)
#pragma unroll
    for (int n = 0; n < 4; ++n) acc[m][n] = (f32x4){0.f, 0.f, 0.f, 0.f};

  gemm256_core<HID / 64>(X + (size_t)bm * 256 * HID,
                         W + (size_t)bn * 256 * HID, HID, HID, lds, acc);

  const int t = threadIdx.x, wid = t >> 6, l = t & 63;
  const int wr = wid >> 2, wc = wid & 3;
  const int lr = l & 15, lg = l >> 4;
#pragma unroll
  for (int m = 0; m < 8; ++m)
#pragma unroll
    for (int n = 0; n < 4; ++n) {
      const int col = bn * 256 + wc * 64 + n * 16 + lr;
      const float bb = bias[col];
#pragma unroll
      for (int r = 0; r < 4; ++r) {
        const int row = bm * 256 + wr * 128 + m * 16 + lg * 4 + r;
        Out[(size_t)row * HID + col] = __float2bfloat16(acc[m][n][r] + bb);
      }
    }
}

// ---------------- scores: out[b] = (QK^T/128) * mask_r * mask_c --------
// grid: (S/256, S/256, BATCH)
__global__ __launch_bounds__(512, 2) void scores_gemm(
    const __hip_bfloat16* __restrict__ Q, const __hip_bfloat16* __restrict__ Km,
    const float* __restrict__ mask, float* __restrict__ out) {
  extern __shared__ char smem[];
  __hip_bfloat16* lds = reinterpret_cast<__hip_bfloat16*>(smem);
  const int b = blockIdx.z;
  const int bm = blockIdx.y, bn = blockIdx.x;

  f32x4 acc[8][4];
#pragma unroll
  for (int m = 0; m < 8; ++m)
#pragma unroll
    for (int n = 0; n < 4; ++n) acc[m][n] = (f32x4){0.f, 0.f, 0.f, 0.f};

  gemm256_core<HID / 64>(Q + ((size_t)b * S_LEN + bm * 256) * HID,
                         Km + ((size_t)b * S_LEN + bn * 256) * HID, HID, HID,
                         lds, acc);

  const int t = threadIdx.x, wid = t >> 6, l = t & 63;
  const int wr = wid >> 2, wc = wid & 3;
  const int lr = l & 15, lg = l >> 4;
  const float inv = 1.0f / 128.0f;   // 1/sqrt(64) * 1/16 heads
#pragma unroll
  for (int m = 0; m < 8; ++m)
#pragma unroll
    for (int n = 0; n < 4; ++n) {
      const int col = bn * 256 + wc * 64 + n * 16 + lr;
      const float mc = mask[b * S_LEN + col] * inv;
#pragma unroll
      for (int r = 0; r < 4; ++r) {
        const int row = bm * 256 + wr * 128 + m * 16 + lg * 4 + r;
        const float mr = mask[b * S_LEN + row];
        out[(size_t)b * S_LEN * S_LEN + (size_t)row * S_LEN + col] =
            acc[m][n][r] * mc * mr;
      }
    }
}

extern "C" void kernel_launch(void* const* d_in, const int* in_sizes, int n_in,
                              void* d_out, int out_size, void* d_ws,
                              size_t ws_size, hipStream_t stream) {
  const float* hs   = (const float*)d_in[0];
  const float* mask = (const float*)d_in[1];
  const float* Wq   = (const float*)d_in[2];
  const float* bq   = (const float*)d_in[3];
  const float* Wk   = (const float*)d_in[4];
  const float* bk   = (const float*)d_in[5];
  float* out = (float*)d_out;

  char* ws = (char*)d_ws;
  __hip_bfloat16* hs_bf = (__hip_bfloat16*)(ws);                 // 16 MB
  __hip_bfloat16* wq_bf = (__hip_bfloat16*)(ws + 16777216);      //  2 MB
  __hip_bfloat16* wk_bf = (__hip_bfloat16*)(ws + 18874368);      //  2 MB
  __hip_bfloat16* q_bf  = (__hip_bfloat16*)(ws + 20971520);      // 16 MB
  __hip_bfloat16* k_bf  = (__hip_bfloat16*)(ws + 37748736);      // 16 MB

  // opt-in to 128 KiB dynamic LDS (no-op/idempotent on ROCm; not a stream op)
  (void)hipFuncSetAttribute((const void*)proj_gemm,
                            hipFuncAttributeMaxDynamicSharedMemorySize, 131072);
  (void)hipFuncSetAttribute((const void*)scores_gemm,
                            hipFuncAttributeMaxDynamicSharedMemorySize, 131072);

  hipLaunchKernelGGL(convert_all, dim3(10240), dim3(256), 0, stream,
                     hs, Wq, Wk, hs_bf, wq_bf, wk_bf);
  hipLaunchKernelGGL(proj_gemm, dim3(HID / 256, M_ROWS / 256, 2), dim3(512),
                     131072, stream, hs_bf, wq_bf, bq, wk_bf, bk, q_bf, k_bf);
  hipLaunchKernelGGL(scores_gemm, dim3(S_LEN / 256, S_LEN / 256, BATCH),
                     dim3(512), 131072, stream, q_bf, k_bf, mask, out);
}